// Round 12
// baseline (372.202 us; speedup 1.0000x reference)
//
#include <hip/hip_runtime.h>
#include <hip/hip_bf16.h>

typedef unsigned short u16;
typedef unsigned int u32;
typedef __attribute__((ext_vector_type(8))) short bf16x8;
typedef __attribute__((ext_vector_type(4))) float f32x4;
typedef __attribute__((ext_vector_type(4))) int   i32x4;
typedef __attribute__((ext_vector_type(4))) float fvec4;
typedef __attribute__((ext_vector_type(4))) unsigned int u32x4;

__device__ inline u16 f2bf(float f) {
    union { float f; unsigned u; } v; v.f = f;
    unsigned r = v.u + 0x7fffu + ((v.u >> 16) & 1u);
    return (u16)(r >> 16);
}

// packed f32x2 -> bf16x2 (RNE), dst.lo = bf16(lo), dst.hi = bf16(hi)
__device__ inline u32 cvtpk(float lo, float hi) {
    u32 r;
    asm("v_cvt_pk_bf16_f32 %0, %1, %2" : "=v"(r) : "v"(lo), "v"(hi));
    return r;
}

__device__ inline f32x4 mfma16(bf16x8 a, bf16x8 b, f32x4 c) {
    return __builtin_amdgcn_mfma_f32_16x16x32_bf16(a, b, c, 0, 0, 0);
}

// async global->LDS, 16B per lane. lds ptr must be wave-uniform; HW adds lane*16.
__device__ inline void gload16(const void* g, void* l) {
    __builtin_amdgcn_global_load_lds(
        (const __attribute__((address_space(1))) unsigned int*)g,
        (__attribute__((address_space(3))) unsigned int*)l, 16, 0, 0);
}

// ---------------------------------------------------------------------------
// All-weights transpose + cast in ONE launch: 4 segments of 32x32 tiles.
// in[K][N] fp32 -> out[N][K] bf16.
// ---------------------------------------------------------------------------
__global__ __launch_bounds__(256)
void transpose_all(const float* __restrict__ w0, u16* __restrict__ o0,   // qkv  K=1024 N=3072
                   const float* __restrict__ w1, u16* __restrict__ o1,   // proj K=1024 N=1024
                   const float* __restrict__ w2, u16* __restrict__ o2,   // fc1  K=1024 N=4096
                   const float* __restrict__ w3, u16* __restrict__ o3) { // fc2  K=4096 N=1024
    __shared__ float tile[32][33];
    int b = blockIdx.x;
    const float* in; u16* out; int K, N, local;
    if (b < 3072)      { in = w0; out = o0; K = 1024; N = 3072; local = b; }
    else if (b < 4096) { in = w1; out = o1; K = 1024; N = 1024; local = b - 3072; }
    else if (b < 8192) { in = w2; out = o2; K = 1024; N = 4096; local = b - 4096; }
    else               { in = w3; out = o3; K = 4096; N = 1024; local = b - 8192; }
    const int nx = N >> 5;
    const int n0 = (local % nx) * 32, k0 = (local / nx) * 32;
    const int x = threadIdx.x & 31, y = threadIdx.x >> 5;
    for (int i = 0; i < 4; ++i)
        tile[y + i * 8][x] = in[(size_t)(k0 + y + i * 8) * N + n0 + x];
    __syncthreads();
    for (int i = 0; i < 4; ++i) {
        int r = y + i * 8;
        out[(size_t)(n0 + r) * K + k0 + x] = f2bf(tile[x][r]);
    }
}

// ---------------------------------------------------------------------------
// V transpose (bf16): qkv[4096][3072] (V = cols 2048..3071) -> vT[1024][4096]
// ---------------------------------------------------------------------------
__global__ __launch_bounds__(256)
void vtrans(const u16* __restrict__ qkv, u16* __restrict__ vT) {
    __shared__ u32 tl[64][33];
    const int t0 = blockIdx.x * 64, f0 = blockIdx.y * 64;
    const int a = threadIdx.x & 31, yy = threadIdx.x >> 5;
    for (int i = 0; i < 8; ++i) {
        int t = yy + i * 8;
        tl[t][a] = *(const u32*)(qkv + (size_t)(t0 + t) * 3072 + 2048 + f0 + a * 2);
    }
    __syncthreads();
    for (int i = 0; i < 8; ++i) {
        int f = yy + i * 8;
        u32 lo = tl[2 * a][f >> 1], hi = tl[2 * a + 1][f >> 1];
        u32 r = (f & 1) ? ((lo >> 16) | (hi & 0xffff0000u))
                        : ((lo & 0xffffu) | (hi << 16));
        *(u32*)(vT + (size_t)(f0 + f) * 4096 + t0 + 2 * a) = r;
    }
}

// ---------------------------------------------------------------------------
// LayerNorm: x[rows][1024] fp32 -> out bf16. One block (256 thr) per row.
// ---------------------------------------------------------------------------
__global__ __launch_bounds__(256)
void ln_kernel(const float* __restrict__ x, const float* __restrict__ g,
               const float* __restrict__ bvec, u16* __restrict__ out) {
    __shared__ float red[2][4];
    const int row = blockIdx.x, tid = threadIdx.x;
    const float* xr = x + (size_t)row * 1024;
    fvec4 v = *(const fvec4*)(xr + tid * 4);
    float s  = v[0] + v[1] + v[2] + v[3];
    float s2 = v[0]*v[0] + v[1]*v[1] + v[2]*v[2] + v[3]*v[3];
    for (int off = 1; off < 64; off <<= 1) {
        s  += __shfl_xor(s,  off);
        s2 += __shfl_xor(s2, off);
    }
    const int w = tid >> 6;
    if ((tid & 63) == 0) { red[0][w] = s; red[1][w] = s2; }
    __syncthreads();
    s  = red[0][0] + red[0][1] + red[0][2] + red[0][3];
    s2 = red[1][0] + red[1][1] + red[1][2] + red[1][3];
    const float mu  = s * (1.0f / 1024.0f);
    const float var = s2 * (1.0f / 1024.0f) - mu * mu;
    const float rstd = rsqrtf(var + 1e-5f);
    fvec4 gv = *(const fvec4*)(g + tid * 4);
    fvec4 bv = *(const fvec4*)(bvec + tid * 4);
    u16 o4[4];
    for (int i = 0; i < 4; ++i)
        o4[i] = f2bf((v[i] - mu) * rstd * gv[i] + bv[i]);
    u32 lo = (u32)o4[0] | ((u32)o4[1] << 16);
    u32 hi = (u32)o4[2] | ((u32)o4[3] << 16);
    u32* dst = (u32*)(out + (size_t)row * 1024 + tid * 4);
    dst[0] = lo; dst[1] = hi;
}

// ---------------------------------------------------------------------------
// reduce4: out = p0+p1+p2+p3 + bias[col] + res. One block per row (1024 f32).
// ---------------------------------------------------------------------------
__global__ __launch_bounds__(256)
void reduce4(const float* __restrict__ p1, const float* __restrict__ p2,
             const float* __restrict__ p3, const float* __restrict__ bias,
             const float* __restrict__ res, float* __restrict__ out) {
    const size_t base = (size_t)blockIdx.x * 1024 + threadIdx.x * 4;
    fvec4 a = *(const fvec4*)(out + base);     // p0 aliases out
    fvec4 b = *(const fvec4*)(p1 + base);
    fvec4 c = *(const fvec4*)(p2 + base);
    fvec4 d = *(const fvec4*)(p3 + base);
    fvec4 r = *(const fvec4*)(res + base);
    fvec4 bi = *(const fvec4*)(bias + threadIdx.x * 4);
    fvec4 o;
#pragma unroll
    for (int i = 0; i < 4; ++i) o[i] = ((a[i] + b[i]) + (c[i] + d[i])) + bi[i] + r[i];
    *(fvec4*)(out + base) = o;
}

// ---------------------------------------------------------------------------
// gemm64: BK=64 single-buffered 128-wide-tile GEMM (kept for proj).
// ---------------------------------------------------------------------------
template <int MODE, int WM, int WN, int MT, int NT, int NYP>
__global__ __launch_bounds__(256)
void gemm64(const u16* __restrict__ A, const u16* __restrict__ Bt,
            const float* __restrict__ bias, const float* __restrict__ res,
            void* __restrict__ out, int M, int N, int K) {
    constexpr int TM = WM * MT * 16;
    constexpr int TN = WN * NT * 16;
    constexpr int AJ = TM / 64;
    constexpr int BJ = TN / 64;
    static_assert(TM == 128, "swizzle assumes 32 M-tiles");
    __shared__ __attribute__((aligned(16))) u16 sA[2 * TM * 32];  // [kt][row][32]
    __shared__ __attribute__((aligned(16))) u16 sB[2 * TN * 32];
    const int id = blockIdx.x;
    const int j  = id >> 3;
    const int by = (id & 7) * NYP + (j >> 5);
    const int bx = j & 31;
    const int tid = threadIdx.x;
    const int lane = tid & 63, w = tid >> 6;
    const int wm = w / WN, wn = w % WN;
    const int q = lane >> 4, l16 = lane & 15;

    f32x4 acc[MT][NT];
#pragma unroll
    for (int i = 0; i < MT; ++i)
#pragma unroll
        for (int jj = 0; jj < NT; ++jj) acc[i][jj] = (f32x4)0.0f;

    const int sr = lane >> 2;            // 0..15
    const int kc = (lane & 3) * 8;       // 0,8,16,24
    const u16* gA[AJ];
    const u16* gB[BJ];
#pragma unroll
    for (int jj = 0; jj < AJ; ++jj)
        gA[jj] = A + (size_t)(bx * TM + (jj * 4 + w) * 16 + sr) * K + kc;
#pragma unroll
    for (int jj = 0; jj < BJ; ++jj)
        gB[jj] = Bt + (size_t)(by * TN + (jj * 4 + w) * 16 + sr) * K + kc;

    for (int k0 = 0; k0 < K; k0 += 64) {
#pragma unroll
        for (int kt = 0; kt < 2; ++kt) {
#pragma unroll
            for (int jj = 0; jj < AJ; ++jj)
                gload16(gA[jj] + k0 + kt * 32, &sA[kt * TM * 32 + (jj * 4 + w) * 512]);
#pragma unroll
            for (int jj = 0; jj < BJ; ++jj)
                gload16(gB[jj] + k0 + kt * 32, &sB[kt * TN * 32 + (jj * 4 + w) * 512]);
        }
        __syncthreads();
#pragma unroll
        for (int kt = 0; kt < 2; ++kt) {
            bf16x8 af[MT], bf[NT];
#pragma unroll
            for (int mt = 0; mt < MT; ++mt)
                af[mt] = *(const bf16x8*)&sA[kt * TM * 32 +
                         (wm * MT * 16 + mt * 16 + l16) * 32 + q * 8];
#pragma unroll
            for (int nt = 0; nt < NT; ++nt)
                bf[nt] = *(const bf16x8*)&sB[kt * TN * 32 +
                         (wn * NT * 16 + nt * 16 + l16) * 32 + q * 8];
#pragma unroll
            for (int mt = 0; mt < MT; ++mt)
#pragma unroll
                for (int nt = 0; nt < NT; ++nt)
                    acc[mt][nt] = mfma16(af[mt], bf[nt], acc[mt][nt]);
        }
        __syncthreads();
    }

#pragma unroll
    for (int mt = 0; mt < MT; ++mt)
#pragma unroll
        for (int nt = 0; nt < NT; ++nt)
#pragma unroll
            for (int r = 0; r < 4; ++r) {
                const int row = bx * TM + wm * MT * 16 + mt * 16 + q * 4 + r;
                const int col = by * TN + wn * NT * 16 + nt * 16 + l16;
                const size_t idx = (size_t)row * N + col;
                float v = acc[mt][nt][r];
                if (MODE == 0) {
                    ((u16*)out)[idx] = f2bf(v);
                } else if (MODE == 1) {
                    ((float*)out)[idx] = v + bias[col] + res[idx];
                } else {
                    float t = v + bias[col];
                    ((u16*)out)[idx] = f2bf(t * 0.5f * (1.0f + erff(t * 0.70710678118f)));
                }
            }
}

// ---------------------------------------------------------------------------
// gemm256 v4 (unchanged — r9-verified, in-run control for the A/B):
// 256x256 tile, BK=64, 8 waves, double-buffered LDS, two super-phases per
// K-tile, each {GISS first -> ds_reads -> sched_barrier(0) -> setprio+MFMA},
// 2 barriers + 1 vmcnt(4) per tile.
// ---------------------------------------------------------------------------
template <int MODE, int SPLIT>
__global__ __launch_bounds__(512)
void gemm256(const u16* __restrict__ A, const u16* __restrict__ Bt,
             const float* __restrict__ bias, const float* __restrict__ res,
             void* __restrict__ out,
             float* __restrict__ q1, float* __restrict__ q2, float* __restrict__ q3,
             int M, int N, int K, int Kc) {
    __shared__ __attribute__((aligned(16))) u16 sA[2][16384];  // 64 KiB
    __shared__ __attribute__((aligned(16))) u16 sB[2][16384];  // 64 KiB
    const int tid  = threadIdx.x;
    const int w    = tid >> 6, lane = tid & 63;
    const int wm   = w >> 2,  wn   = w & 3;
    const int q    = lane >> 4, l16 = lane & 15;
    const int w8   = w << 3,  l8   = lane >> 3;       // l8 in 0..7
    const int kch  = (lane & 7) ^ l8;                  // inverse-swizzled src chunk

    const int nwg  = gridDim.x;
    const int id   = blockIdx.x;
    const int wgid = (id & 7) * (nwg >> 3) + (id >> 3);
    int bx, by, sp;
    if (SPLIT == 1) { bx = wgid & 15; by = wgid >> 4; sp = 0; }
    else            { bx = wgid & 15; by = (wgid >> 4) & 3; sp = wgid >> 6; }

    const u16* pAs = A  + (size_t)(bx * 256 + w8 + l8) * K + kch * 8 + (size_t)sp * Kc;
    const u16* pBs = Bt + (size_t)(by * 256 + w8 + l8) * K + kch * 8 + (size_t)sp * Kc;

    const int cs0  = ((q ^ (l16 & 7)) << 4);
    const int cs1  = cs0 ^ 64;
    const int aoff = (wm * 128 + l16) * 128;
    const int boff = (wn * 64  + l16) * 128;

    f32x4 acc[8][4];
#pragma unroll
    for (int m = 0; m < 8; ++m)
#pragma unroll
        for (int n = 0; n < 4; ++n) acc[m][n] = (f32x4)0.0f;

#define GISS(P, r0, k0, SH, b_) \
    gload16((P) + (size_t)((r0) * K + (k0)), &SH[b_][((r0) + w8) * 64])

    GISS(pBs, 0, 0, sB, 0);   GISS(pBs, 64, 0, sB, 0);
    GISS(pBs, 128, 0, sB, 0); GISS(pBs, 192, 0, sB, 0);
    GISS(pAs, 0, 0, sA, 0);   GISS(pAs, 64, 0, sA, 0);
    GISS(pAs, 128, 0, sA, 0); GISS(pAs, 192, 0, sA, 0);
    GISS(pBs, 0, 64, sB, 1);  GISS(pBs, 64, 64, sB, 1);
    GISS(pBs, 128, 64, sB, 1);GISS(pBs, 192, 64, sB, 1);
    asm volatile("s_waitcnt vmcnt(4)" ::: "memory");
    __builtin_amdgcn_s_barrier();

    const int NT_ = Kc >> 6;
    for (int t = 0; t < NT_; ++t) {
        const int b  = t & 1;
        const char* bA_ = (const char*)&sA[b][0] + aoff;
        const char* bB_ = (const char*)&sB[b][0] + boff;
        const int kA = (t + 1 < NT_ ? t + 1 : t) << 6;
        const int kB = (t + 2 < NT_ ? t + 2 : t) << 6;

        if (b) { GISS(pAs, 0, kA, sA, 0); GISS(pAs, 64, kA, sA, 0);
                 GISS(pAs, 128, kA, sA, 0); GISS(pAs, 192, kA, sA, 0); }
        else   { GISS(pAs, 0, kA, sA, 1); GISS(pAs, 64, kA, sA, 1);
                 GISS(pAs, 128, kA, sA, 1); GISS(pAs, 192, kA, sA, 1); }
        bf16x8 bfr[4][2];
#pragma unroll
        for (int n = 0; n < 4; ++n) {
            bfr[n][0] = *(const bf16x8*)(bB_ + n * 2048 + cs0);
            bfr[n][1] = *(const bf16x8*)(bB_ + n * 2048 + cs1);
        }
        bf16x8 af[4][2];
#pragma unroll
        for (int m = 0; m < 4; ++m) {
            af[m][0] = *(const bf16x8*)(bA_ + m * 2048 + cs0);
            af[m][1] = *(const bf16x8*)(bA_ + m * 2048 + cs1);
        }
        __builtin_amdgcn_sched_barrier(0);
        __builtin_amdgcn_s_setprio(1);
#pragma unroll
        for (int kt = 0; kt < 2; ++kt)
#pragma unroll
            for (int m = 0; m < 4; ++m)
#pragma unroll
                for (int n = 0; n < 4; ++n)
                    acc[m][n] = mfma16(af[m][kt], bfr[n][kt], acc[m][n]);
        __builtin_amdgcn_s_setprio(0);
        __builtin_amdgcn_s_barrier();

        if (b) { GISS(pBs, 0, kB, sB, 1); GISS(pBs, 64, kB, sB, 1);
                 GISS(pBs, 128, kB, sB, 1); GISS(pBs, 192, kB, sB, 1); }
        else   { GISS(pBs, 0, kB, sB, 0); GISS(pBs, 64, kB, sB, 0);
                 GISS(pBs, 128, kB, sB, 0); GISS(pBs, 192, kB, sB, 0); }
        bf16x8 ag[4][2];
#pragma unroll
        for (int m = 0; m < 4; ++m) {
            ag[m][0] = *(const bf16x8*)(bA_ + (4 + m) * 2048 + cs0);
            ag[m][1] = *(const bf16x8*)(bA_ + (4 + m) * 2048 + cs1);
        }
        __builtin_amdgcn_sched_barrier(0);
        __builtin_amdgcn_s_setprio(1);
#pragma unroll
        for (int kt = 0; kt < 2; ++kt)
#pragma unroll
            for (int m = 0; m < 4; ++m)
#pragma unroll
                for (int n = 0; n < 4; ++n)
                    acc[4 + m][n] = mfma16(ag[m][kt], bfr[n][kt], acc[4 + m][n]);
        __builtin_amdgcn_s_setprio(0);
        asm volatile("s_waitcnt vmcnt(4)" ::: "memory");
        __builtin_amdgcn_s_barrier();
    }
#undef GISS

    float* po = nullptr;
    if (MODE == 3)
        po = sp == 0 ? (float*)out : sp == 1 ? q1 : sp == 2 ? q2 : q3;

#pragma unroll
    for (int m = 0; m < 8; ++m)
#pragma unroll
        for (int n = 0; n < 4; ++n)
#pragma unroll
            for (int r = 0; r < 4; ++r) {
                const int row = bx * 256 + wm * 128 + m * 16 + q * 4 + r;
                const int col = by * 256 + wn * 64 + n * 16 + l16;
                const size_t idx = (size_t)row * N + col;
                float v = acc[m][n][r];
                if (MODE == 0) {
                    ((u16*)out)[idx] = f2bf(v);
                } else if (MODE == 1) {
                    ((float*)out)[idx] = v + bias[col] + res[idx];
                } else if (MODE == 2) {
                    float t = v + bias[col];
                    ((u16*)out)[idx] = f2bf(t * 0.5f * (1.0f + erff(t * 0.70710678118f)));
                } else {
                    po[idx] = v;
                }
            }
}

// ---------------------------------------------------------------------------
// gemm128b32: 128x128 tile, BK=32, 4 waves (2Mx2N), TRIPLE-buffered LDS
// (3 x 16 KiB = 48 KiB -> 3 blocks/CU = 12 waves/CU, the m97/m114 implicit-
// overlap regime every prior variant starved at 8 waves/CU).
// One phase per K-tile: {stage tile t+2 (4 GISS, distance-2) -> 8 ds_read ->
// sched_barrier(0) -> setprio + 16 MFMA -> vmcnt(4) -> barrier}.
// vmcnt audit: tile t staged at iter t-2, retired by iter t-1's vmcnt(4),
// read at iter t. WAR: buf (t+2)%3's old tile t-1 was read at iter t-1,
// done before its barrier; iter t's stages issue after. Clamped dead
// stages at the tail keep counts exact.
// Swizzle (BK=32: 4 chunks of 16B per 64B row): LDS[row][c] holds global
// chunk c ^ ((row>>1)&3); applied on per-lane global source (linear LDS
// dest) and on ds_read addr -> 2-way banks (free, m136).
// ---------------------------------------------------------------------------
template <int MODE>
__global__ __launch_bounds__(256)
void gemm128b32(const u16* __restrict__ A, const u16* __restrict__ Bt,
                const float* __restrict__ bias, const float* __restrict__ res,
                void* __restrict__ out, int M, int N, int K) {
    __shared__ __attribute__((aligned(16))) u16 sA[3][4096];   // 8 KiB x3
    __shared__ __attribute__((aligned(16))) u16 sB[3][4096];   // 8 KiB x3
    const int tid  = threadIdx.x;
    const int w    = tid >> 6, lane = tid & 63;
    const int wm   = w >> 1,  wn   = w & 1;
    const int q    = lane >> 4, l16 = lane & 15;
    const int w16  = w << 4;                           // wave's 16-row group
    const int srow = w16 + (lane >> 2);                // staging row (per lane)
    const int csrc = (lane & 3) ^ ((lane >> 3) & 3);   // inverse-swizzled chunk

    // bijective XCD swizzle (nwg % 8 == 0 for call sites: 768, 1024)
    const int nwg  = gridDim.x;
    const int id   = blockIdx.x;
    const int wgid = (id & 7) * (nwg >> 3) + (id >> 3);
    const int bx   = wgid & 31, by = wgid >> 5;        // M = 4096 -> 32 row tiles

    // per-lane global staging bases
    const u16* pAs = A  + (size_t)(bx * 128 + srow) * K + csrc * 8;
    const u16* pBs = Bt + (size_t)(by * 128 + srow) * K + csrc * 8;

    // swizzled ds_read byte offset: chunk = q ^ ((l16>>1)&3), row stride 64B
    const int cs   = ((q ^ ((l16 >> 1) & 3)) << 4);
    const int aoff = (wm * 64 + l16) * 64;
    const int boff = (wn * 64 + l16) * 64;

    f32x4 acc[4][4];
#pragma unroll
    for (int m = 0; m < 4; ++m)
#pragma unroll
        for (int n = 0; n < 4; ++n) acc[m][n] = (f32x4)0.0f;

#define GISS(P, r0, k0, SH, b_) \
    gload16((P) + (size_t)((r0) * K + (k0)), &SH[b_][((r0) + w16) * 32])

    // prologue: tile0 -> buf0, tile1 -> buf1 (8 issues, A+B each 2)
    GISS(pAs, 0, 0, sA, 0);  GISS(pAs, 64, 0, sA, 0);
    GISS(pBs, 0, 0, sB, 0);  GISS(pBs, 64, 0, sB, 0);
    GISS(pAs, 0, 32, sA, 1); GISS(pAs, 64, 32, sA, 1);
    GISS(pBs, 0, 32, sB, 1); GISS(pBs, 64, 32, sB, 1);
    asm volatile("s_waitcnt vmcnt(4)" ::: "memory");   // tile0 landed; tile1 flying
    __builtin_amdgcn_s_barrier();

    const int NT_ = K >> 5;             // K-tiles of 32; K % 32 == 0, NT_ >= 2
    int buf = 0;
    for (int t = 0; t < NT_; ++t) {
        const int nb = buf + 2 >= 3 ? buf - 1 : buf + 2;   // (t+2) % 3
        const int kS = (t + 2 < NT_ ? t + 2 : NT_ - 1) << 5;  // clamp dead

        // stage tile t+2 -> buf nb
        GISS(pAs, 0, kS, sA, nb); GISS(pAs, 64, kS, sA, nb);
        GISS(pBs, 0, kS, sB, nb); GISS(pBs, 64, kS, sB, nb);

        const char* bA_ = (const char*)&sA[buf][0] + aoff;
        const char* bB_ = (const char*)&sB[buf][0] + boff;
        bf16x8 af[4], bfr[4];
#pragma unroll
        for (int m = 0; m < 4; ++m)
            af[m] = *(const bf16x8*)(bA_ + m * 1024 + cs);
#pragma unroll
        for (int n = 0; n < 4; ++n)
            bfr[n] = *(const bf16x8*)(bB_ + n * 1024 + cs);

        __builtin_amdgcn_sched_barrier(0);   // stages+reads issued before MFMAs
        __builtin_amdgcn_s_setprio(1);
#pragma unroll
        for (int m = 0; m < 4; ++m)
#pragma unroll
            for (int n = 0; n < 4; ++n)
                acc[m][n] = mfma16(af[m], bfr[n], acc[m][n]);
        __builtin_amdgcn_s_setprio(0);
        asm volatile("s_waitcnt vmcnt(4)" ::: "memory");   // t+1 landed; t+2 flying
        __builtin_amdgcn_s_barrier();

        buf = buf + 1 >= 3 ? 0 : buf + 1;
    }
#undef GISS

#pragma unroll
    for (int m = 0; m < 4; ++m)
#pragma unroll
        for (int n = 0; n < 4; ++n)
#pragma unroll
            for (int r = 0; r < 4; ++r) {
                const int row = bx * 128 + wm * 64 + m * 16 + q * 4 + r;
                const int col = by * 128 + wn * 64 + n * 16 + l16;
                const size_t idx = (size_t)row * N + col;
                float v = acc[m][n][r];
                if (MODE == 0) {
                    ((u16*)out)[idx] = f2bf(v);
                } else if (MODE == 1) {
                    ((float*)out)[idx] = v + bias[col] + res[idx];
                } else {
                    float t = v + bias[col];
                    ((u16*)out)[idx] = f2bf(t * 0.5f * (1.0f + erff(t * 0.70710678118f)));
                }
            }
}

// ---------------------------------------------------------------------------
// Flash attention v7 (unchanged from round 9 — recovered): r4 structure +
// Q pre-scale + raw v_exp_f32 + cvtpk pack + MFMA ones-trick row-sum.
// ---------------------------------------------------------------------------
__global__ __launch_bounds__(256)
void attention3(const u16* __restrict__ qkv, const u16* __restrict__ vT,
                u16* __restrict__ o) {
    __shared__ __attribute__((aligned(16))) u16 sK[64][72];   // [key][d]
    __shared__ __attribute__((aligned(16))) u16 sV[64][72];   // [d][key]

    const int tid = threadIdx.x;
    const int lane = tid & 63, w = tid >> 6;
    const int qc = lane >> 4, l16 = lane & 15;
    const int bx = blockIdx.x;
    const int qt = bx & 15, h = (bx >> 4) & 15, b = bx >> 8;
    const int rowbase = qt * 128 + w * 32;

    const float SC = 0.18033688f;   // log2(e)/8, folded into Q once

    bf16x8 aQ[2][2];
#pragma unroll
    for (int mtq = 0; mtq < 2; ++mtq)
#pragma unroll
        for (int kd = 0; kd < 2; ++kd) {
            bf16x8 qv = *(const bf16x8*)(qkv +
                (size_t)(b * 2048 + rowbase + mtq * 16 + l16) * 3072 +
                h * 64 + kd * 32 + qc * 8);
            u32x4 pw;
#pragma unroll
            for (int i = 0; i < 4; ++i) {
                union { u32 u; float f; } lo, hi;
                lo.u = (u32)(u16)(short)qv[2 * i]     << 16;
                hi.u = (u32)(u16)(short)qv[2 * i + 1] << 16;
                pw[i] = cvtpk(lo.f * SC, hi.f * SC);
            }
            aQ[mtq][kd] = *(const bf16x8*)&pw;
        }

    f32x4 accO[2][4];
#pragma unroll
    for (int mtq = 0; mtq < 2; ++mtq)
#pragma unroll
        for (int dt = 0; dt < 4; ++dt) accO[mtq][dt] = (f32x4)0.0f;
    f32x4 accS[2];
    accS[0] = (f32x4)0.0f; accS[1] = (f32x4)0.0f;

    bf16x8 vone;
#pragma unroll
    for (int i = 0; i < 8; ++i) vone[i] = (short)0x3F80;   // bf16 1.0

    const int srr = tid >> 3;            // 0..31
    const int sc8 = (tid & 7) * 8;       // 0..56
    const u16* gK = qkv + (size_t)(b * 2048 + srr) * 3072 + 1024 + h * 64 + sc8;
    const u16* gV = vT + (size_t)(h * 64 + srr) * 4096 + b * 2048 + sc8;

    i32x4 cK[2], cV[2];
    cK[0] = *(const i32x4*)gK;
    cK[1] = *(const i32x4*)(gK + (size_t)32 * 3072);
    cV[0] = *(const i32x4*)gV;
    cV[1] = *(const i32x4*)(gV + (size_t)32 * 4096);

    const int sig_base = ((l16 >> 2) << 3) + (l16 & 3);   // q*8 + r

    for (int kc = 0; kc < 32; ++kc) {
        __syncthreads();
        *(i32x4*)&sK[srr][sc8]      = cK[0];
        *(i32x4*)&sK[srr + 32][sc8] = cK[1];
        *(i32x4*)&sV[srr][sc8]      = cV[0];
        *(i32x4*)&sV[srr + 32][sc8] = cV[1];
        const int kn = (kc + 1 < 32) ? kc + 1 : 31;
        i32x4 nK[2], nV[2];
        nK[0] = *(const i32x4*)(gK + (size_t)kn * 64 * 3072);
        nK[1] = *(const i32x4*)(gK + ((size_t)kn * 64 + 32) * 3072);
        nV[0] = *(const i32x4*)(gV + kn * 64);
        nV[1] = *(const i32x4*)(gV + (size_t)32 * 4096 + kn * 64);
        __syncthreads();

        bf16x8 kf[4][2];
#pragma unroll
        for (int mk = 0; mk < 4; ++mk) {
            const int krow = ((mk & 1) << 5) + ((mk >> 1) << 2) + sig_base;
            kf[mk][0] = *(const bf16x8*)&sK[krow][qc * 8];
            kf[mk][1] = *(const bf16x8*)&sK[krow][32 + qc * 8];
        }

        f32x4 s[2][4];
#pragma unroll
        for (int mtq = 0; mtq < 2; ++mtq)
#pragma unroll
            for (int mk = 0; mk < 4; ++mk) {
                f32x4 z = (f32x4)0.0f;
                z = mfma16(kf[mk][0], aQ[mtq][0], z);
                z = mfma16(kf[mk][1], aQ[mtq][1], z);
                s[mtq][mk] = z;
            }

        bf16x8 pf[2][2];
#pragma unroll
        for (int mtq = 0; mtq < 2; ++mtq) {
#pragma unroll
            for (int mk = 0; mk < 4; ++mk)
#pragma unroll
                for (int r = 0; r < 4; ++r)
                    s[mtq][mk][r] = __builtin_amdgcn_exp2f(s[mtq][mk][r]);
#pragma unroll
            for (int kt = 0; kt < 2; ++kt) {
                u32x4 pw;
                pw[0] = cvtpk(s[mtq][kt][0],     s[mtq][kt][1]);
                pw[1] = cvtpk(s[mtq][kt][2],     s[mtq][kt][3]);
                pw[2] = cvtpk(s[mtq][2 + kt][0], s[mtq][2 + kt][1]);
                pw[3] = cvtpk(s[mtq][2 + kt][2], s[mtq][2 + kt][3]);
                pf[mtq][kt] = *(const bf16x8*)&pw;
            }
        }

#pragma unroll
        for (int kt = 0; kt < 2; ++kt) {
#pragma unroll
            for (int dt = 0; dt < 4; ++dt) {
                bf16x8 vf = *(const bf16x8*)&sV[dt * 16 + l16][kt * 32 + qc * 8];
#pragma unroll
                for (int mtq = 0; mtq < 2; ++mtq)
                    accO[mtq][dt] = mfma16(pf[mtq][kt], vf, accO[mtq][dt]);
            }
#pragma unroll
            for (int mtq = 0; mtq < 2; ++mtq)
                accS[mtq] = mfma16(pf[mtq][kt], vone, accS[mtq]);
        }

        cK[0] = nK[0]; cK[1] = nK[1];
        cV[0] = nV[0]; cV[1] = nV[1];
    }

#pragma unroll
    for (int mtq = 0; mtq < 2; ++mtq)
#pragma unroll
        for (int r = 0; r < 4; ++r) {
            const float inv = 1.0f / accS[mtq][r];
            const size_t tok = (size_t)b * 2048 + rowbase + mtq * 16 + qc * 4 + r;
#pragma unroll
            for (int dt = 0; dt < 4; ++dt)
                o[tok * 1024 + h * 64 + dt * 16 + l16] = f2bf(accO[mtq][dt][r] * inv);
        }
}

// ---------------------------------------------------------------------------
extern "C" void kernel_launch(void* const* d_in, const int* in_sizes, int n_in,
                              void* d_out, int out_size, void* d_ws, size_t ws_size,
                              hipStream_t stream) {
    const float* x      = (const float*)d_in[0];
    const float* ln1_g  = (const float*)d_in[1];
    const float* ln1_b  = (const float*)d_in[2];
    const float* w_qkv  = (const float*)d_in[3];
    const float* w_proj = (const float*)d_in[4];
    const float* b_proj = (const float*)d_in[5];
    const float* ln2_g  = (const float*)d_in[6];
    const float* ln2_b  = (const float*)d_in[7];
    const float* w_fc1  = (const float*)d_in[8];
    const float* b_fc1  = (const float*)d_in[9];
    const float* w_fc2  = (const float*)d_in[10];
    const float* b_fc2  = (const float*)d_in[11];
    float* out = (float*)d_out;

    // workspace layout (bytes); total ~104 MB
    char* ws = (char*)d_ws;
    u16*   wqkvT  = (u16*)(ws + 0);           //  6 MB  [3072][1024]
    u16*   wprojT = (u16*)(ws + 6291456);     //  2 MB  [1024][1024]
    u16*   wfc1T  = (u16*)(ws + 8388608);     //  8 MB  [4096][1024]
    u16*   wfc2T  = (u16*)(ws + 16777216);    //  8 MB  [1024][4096]
    u16*   hA     = (u16*)(ws + 25165824);    //  8 MB  ln1 out; reused for attn out
    u16*   qkv    = (u16*)(ws + 33554432);    // 24 MB  [4096][3072]; reused for h2
    float* x1     = (float*)(ws + 58720256);  // 16 MB  [4096][1024] fp32
    u16*   gbuf   = (u16*)(ws + 75497472);    // 32 MB  [4096][4096] gelu out
    u16*   vT     = (u16*)(ws + 75497472);    //  8 MB  aliases gbuf (dead before fc1)
    // fc2 split-K fp32 partials (regions dead by fc2 time):
    float* p1     = (float*)(ws + 0);         // 16 MB over wqkvT/wprojT/wfc1T
    float* p2     = (float*)(ws + 25165824);  // 16 MB over hA + qkv head
    float* p3     = (float*)(ws + 41943040);  // 16 MB over qkv tail (ends at x1)

    dim3 blk(256);
    transpose_all<<<12288, blk, 0, stream>>>(w_qkv, wqkvT, w_proj, wprojT,
                                             w_fc1, wfc1T, w_fc2, wfc2T);

    ln_kernel<<<4096, blk, 0, stream>>>(x, ln1_g, ln1_b, hA);
    gemm128b32<0><<<768, blk, 0, stream>>>(hA, wqkvT, nullptr, nullptr, qkv, 4096, 3072, 1024);
    vtrans<<<dim3(64, 16), blk, 0, stream>>>(qkv, vT);
    attention3<<<512, blk, 0, stream>>>(qkv, vT, hA);
    gemm64<1, 4, 1, 2, 4, 2><<<512, blk, 0, stream>>>(hA, wprojT, b_proj, x, x1, 4096, 1024, 1024);

    u16* h2 = qkv;  // qkv dead after attention
    ln_kernel<<<4096, blk, 0, stream>>>(x1, ln2_g, ln2_b, h2);
    gemm128b32<2><<<1024, blk, 0, stream>>>(h2, wfc1T, b_fc1, nullptr, gbuf, 4096, 4096, 1024);
    // fc2: split-K x4 (Kc=1024), raw fp32 partials; p0 = out (gemm256 = in-run control)
    gemm256<3, 4><<<256, dim3(512), 0, stream>>>(gbuf, wfc2T, nullptr, nullptr, out,
                                                 p1, p2, p3, 4096, 1024, 4096, 1024);
    reduce4<<<4096, blk, 0, stream>>>(p1, p2, p3, b_fc2, x1, out);
}

// Round 13
// 342.048 us; speedup vs baseline: 1.0882x; 1.0882x over previous
//
#include <hip/hip_runtime.h>
#include <hip/hip_bf16.h>

typedef unsigned short u16;
typedef unsigned int u32;
typedef __attribute__((ext_vector_type(8))) short bf16x8;
typedef __attribute__((ext_vector_type(4))) float f32x4;
typedef __attribute__((ext_vector_type(4))) int   i32x4;
typedef __attribute__((ext_vector_type(4))) float fvec4;
typedef __attribute__((ext_vector_type(4))) unsigned int u32x4;

__device__ inline u16 f2bf(float f) {
    union { float f; unsigned u; } v; v.f = f;
    unsigned r = v.u + 0x7fffu + ((v.u >> 16) & 1u);
    return (u16)(r >> 16);
}

// packed f32x2 -> bf16x2 (RNE), dst.lo = bf16(lo), dst.hi = bf16(hi)
__device__ inline u32 cvtpk(float lo, float hi) {
    u32 r;
    asm("v_cvt_pk_bf16_f32 %0, %1, %2" : "=v"(r) : "v"(lo), "v"(hi));
    return r;
}

// fast GELU (tanh form): t * sigmoid(1.5957691*(t + 0.044715 t^3))
//  = t * rcp(1 + exp2(-2.3021876*(t + 0.044715 t^3)))
// ~8 VALU ops w/ hw v_exp+v_rcp vs ~25 for OCML erff; |err vs exact-erf
// GELU| < 1e-3 absolute, below bf16 output quantization.
__device__ inline float fast_gelu(float t) {
    float w = t + 0.044715f * t * t * t;
    float e = __builtin_amdgcn_exp2f(-2.3021876f * w);
    return t * __builtin_amdgcn_rcpf(1.0f + e);
}

__device__ inline f32x4 mfma16(bf16x8 a, bf16x8 b, f32x4 c) {
    return __builtin_amdgcn_mfma_f32_16x16x32_bf16(a, b, c, 0, 0, 0);
}

// async global->LDS, 16B per lane. lds ptr must be wave-uniform; HW adds lane*16.
__device__ inline void gload16(const void* g, void* l) {
    __builtin_amdgcn_global_load_lds(
        (const __attribute__((address_space(1))) unsigned int*)g,
        (__attribute__((address_space(3))) unsigned int*)l, 16, 0, 0);
}

// ---------------------------------------------------------------------------
// All-weights transpose + cast in ONE launch: 4 segments of 32x32 tiles.
// in[K][N] fp32 -> out[N][K] bf16.
// ---------------------------------------------------------------------------
__global__ __launch_bounds__(256)
void transpose_all(const float* __restrict__ w0, u16* __restrict__ o0,   // qkv  K=1024 N=3072
                   const float* __restrict__ w1, u16* __restrict__ o1,   // proj K=1024 N=1024
                   const float* __restrict__ w2, u16* __restrict__ o2,   // fc1  K=1024 N=4096
                   const float* __restrict__ w3, u16* __restrict__ o3) { // fc2  K=4096 N=1024
    __shared__ float tile[32][33];
    int b = blockIdx.x;
    const float* in; u16* out; int K, N, local;
    if (b < 3072)      { in = w0; out = o0; K = 1024; N = 3072; local = b; }
    else if (b < 4096) { in = w1; out = o1; K = 1024; N = 1024; local = b - 3072; }
    else if (b < 8192) { in = w2; out = o2; K = 1024; N = 4096; local = b - 4096; }
    else               { in = w3; out = o3; K = 4096; N = 1024; local = b - 8192; }
    const int nx = N >> 5;
    const int n0 = (local % nx) * 32, k0 = (local / nx) * 32;
    const int x = threadIdx.x & 31, y = threadIdx.x >> 5;
    for (int i = 0; i < 4; ++i)
        tile[y + i * 8][x] = in[(size_t)(k0 + y + i * 8) * N + n0 + x];
    __syncthreads();
    for (int i = 0; i < 4; ++i) {
        int r = y + i * 8;
        out[(size_t)(n0 + r) * K + k0 + x] = f2bf(tile[x][r]);
    }
}

// ---------------------------------------------------------------------------
// V transpose (bf16): qkv[4096][3072] (V = cols 2048..3071) -> vT[1024][4096]
// ---------------------------------------------------------------------------
__global__ __launch_bounds__(256)
void vtrans(const u16* __restrict__ qkv, u16* __restrict__ vT) {
    __shared__ u32 tl[64][33];
    const int t0 = blockIdx.x * 64, f0 = blockIdx.y * 64;
    const int a = threadIdx.x & 31, yy = threadIdx.x >> 5;
    for (int i = 0; i < 8; ++i) {
        int t = yy + i * 8;
        tl[t][a] = *(const u32*)(qkv + (size_t)(t0 + t) * 3072 + 2048 + f0 + a * 2);
    }
    __syncthreads();
    for (int i = 0; i < 8; ++i) {
        int f = yy + i * 8;
        u32 lo = tl[2 * a][f >> 1], hi = tl[2 * a + 1][f >> 1];
        u32 r = (f & 1) ? ((lo >> 16) | (hi & 0xffff0000u))
                        : ((lo & 0xffffu) | (hi << 16));
        *(u32*)(vT + (size_t)(f0 + f) * 4096 + t0 + 2 * a) = r;
    }
}

// ---------------------------------------------------------------------------
// LayerNorm: x[rows][1024] fp32 -> out bf16. One block (256 thr) per row.
// ---------------------------------------------------------------------------
__global__ __launch_bounds__(256)
void ln_kernel(const float* __restrict__ x, const float* __restrict__ g,
               const float* __restrict__ bvec, u16* __restrict__ out) {
    __shared__ float red[2][4];
    const int row = blockIdx.x, tid = threadIdx.x;
    const float* xr = x + (size_t)row * 1024;
    fvec4 v = *(const fvec4*)(xr + tid * 4);
    float s  = v[0] + v[1] + v[2] + v[3];
    float s2 = v[0]*v[0] + v[1]*v[1] + v[2]*v[2] + v[3]*v[3];
    for (int off = 1; off < 64; off <<= 1) {
        s  += __shfl_xor(s,  off);
        s2 += __shfl_xor(s2, off);
    }
    const int w = tid >> 6;
    if ((tid & 63) == 0) { red[0][w] = s; red[1][w] = s2; }
    __syncthreads();
    s  = red[0][0] + red[0][1] + red[0][2] + red[0][3];
    s2 = red[1][0] + red[1][1] + red[1][2] + red[1][3];
    const float mu  = s * (1.0f / 1024.0f);
    const float var = s2 * (1.0f / 1024.0f) - mu * mu;
    const float rstd = rsqrtf(var + 1e-5f);
    fvec4 gv = *(const fvec4*)(g + tid * 4);
    fvec4 bv = *(const fvec4*)(bvec + tid * 4);
    u16 o4[4];
    for (int i = 0; i < 4; ++i)
        o4[i] = f2bf((v[i] - mu) * rstd * gv[i] + bv[i]);
    u32 lo = (u32)o4[0] | ((u32)o4[1] << 16);
    u32 hi = (u32)o4[2] | ((u32)o4[3] << 16);
    u32* dst = (u32*)(out + (size_t)row * 1024 + tid * 4);
    dst[0] = lo; dst[1] = hi;
}

// ---------------------------------------------------------------------------
// reduce4: out = p0+p1+p2+p3 + bias[col] + res. One block per row (1024 f32).
// ---------------------------------------------------------------------------
__global__ __launch_bounds__(256)
void reduce4(const float* __restrict__ p1, const float* __restrict__ p2,
             const float* __restrict__ p3, const float* __restrict__ bias,
             const float* __restrict__ res, float* __restrict__ out) {
    const size_t base = (size_t)blockIdx.x * 1024 + threadIdx.x * 4;
    fvec4 a = *(const fvec4*)(out + base);     // p0 aliases out
    fvec4 b = *(const fvec4*)(p1 + base);
    fvec4 c = *(const fvec4*)(p2 + base);
    fvec4 d = *(const fvec4*)(p3 + base);
    fvec4 r = *(const fvec4*)(res + base);
    fvec4 bi = *(const fvec4*)(bias + threadIdx.x * 4);
    fvec4 o;
#pragma unroll
    for (int i = 0; i < 4; ++i) o[i] = ((a[i] + b[i]) + (c[i] + d[i])) + bi[i] + r[i];
    *(fvec4*)(out + base) = o;
}

// ---------------------------------------------------------------------------
// gemm64: BK=64 single-buffered 128-wide-tile GEMM (kept for proj).
// ---------------------------------------------------------------------------
template <int MODE, int WM, int WN, int MT, int NT, int NYP>
__global__ __launch_bounds__(256)
void gemm64(const u16* __restrict__ A, const u16* __restrict__ Bt,
            const float* __restrict__ bias, const float* __restrict__ res,
            void* __restrict__ out, int M, int N, int K) {
    constexpr int TM = WM * MT * 16;
    constexpr int TN = WN * NT * 16;
    constexpr int AJ = TM / 64;
    constexpr int BJ = TN / 64;
    static_assert(TM == 128, "swizzle assumes 32 M-tiles");
    __shared__ __attribute__((aligned(16))) u16 sA[2 * TM * 32];  // [kt][row][32]
    __shared__ __attribute__((aligned(16))) u16 sB[2 * TN * 32];
    const int id = blockIdx.x;
    const int j  = id >> 3;
    const int by = (id & 7) * NYP + (j >> 5);
    const int bx = j & 31;
    const int tid = threadIdx.x;
    const int lane = tid & 63, w = tid >> 6;
    const int wm = w / WN, wn = w % WN;
    const int q = lane >> 4, l16 = lane & 15;

    f32x4 acc[MT][NT];
#pragma unroll
    for (int i = 0; i < MT; ++i)
#pragma unroll
        for (int jj = 0; jj < NT; ++jj) acc[i][jj] = (f32x4)0.0f;

    const int sr = lane >> 2;            // 0..15
    const int kc = (lane & 3) * 8;       // 0,8,16,24
    const u16* gA[AJ];
    const u16* gB[BJ];
#pragma unroll
    for (int jj = 0; jj < AJ; ++jj)
        gA[jj] = A + (size_t)(bx * TM + (jj * 4 + w) * 16 + sr) * K + kc;
#pragma unroll
    for (int jj = 0; jj < BJ; ++jj)
        gB[jj] = Bt + (size_t)(by * TN + (jj * 4 + w) * 16 + sr) * K + kc;

    for (int k0 = 0; k0 < K; k0 += 64) {
#pragma unroll
        for (int kt = 0; kt < 2; ++kt) {
#pragma unroll
            for (int jj = 0; jj < AJ; ++jj)
                gload16(gA[jj] + k0 + kt * 32, &sA[kt * TM * 32 + (jj * 4 + w) * 512]);
#pragma unroll
            for (int jj = 0; jj < BJ; ++jj)
                gload16(gB[jj] + k0 + kt * 32, &sB[kt * TN * 32 + (jj * 4 + w) * 512]);
        }
        __syncthreads();
#pragma unroll
        for (int kt = 0; kt < 2; ++kt) {
            bf16x8 af[MT], bf[NT];
#pragma unroll
            for (int mt = 0; mt < MT; ++mt)
                af[mt] = *(const bf16x8*)&sA[kt * TM * 32 +
                         (wm * MT * 16 + mt * 16 + l16) * 32 + q * 8];
#pragma unroll
            for (int nt = 0; nt < NT; ++nt)
                bf[nt] = *(const bf16x8*)&sB[kt * TN * 32 +
                         (wn * NT * 16 + nt * 16 + l16) * 32 + q * 8];
#pragma unroll
            for (int mt = 0; mt < MT; ++mt)
#pragma unroll
                for (int nt = 0; nt < NT; ++nt)
                    acc[mt][nt] = mfma16(af[mt], bf[nt], acc[mt][nt]);
        }
        __syncthreads();
    }

#pragma unroll
    for (int mt = 0; mt < MT; ++mt)
#pragma unroll
        for (int nt = 0; nt < NT; ++nt)
#pragma unroll
            for (int r = 0; r < 4; ++r) {
                const int row = bx * TM + wm * MT * 16 + mt * 16 + q * 4 + r;
                const int col = by * TN + wn * NT * 16 + nt * 16 + l16;
                const size_t idx = (size_t)row * N + col;
                float v = acc[mt][nt][r];
                if (MODE == 0) {
                    ((u16*)out)[idx] = f2bf(v);
                } else if (MODE == 1) {
                    ((float*)out)[idx] = v + bias[col] + res[idx];
                } else {
                    ((u16*)out)[idx] = f2bf(fast_gelu(v + bias[col]));
                }
            }
}

// ---------------------------------------------------------------------------
// gemm256 v4 (r9-verified loop; MODE 2 epilogue now uses fast_gelu):
// 256x256 tile, BK=64, 8 waves, double-buffered LDS, two super-phases per
// K-tile, each {GISS first -> ds_reads -> sched_barrier(0) -> setprio+MFMA},
// 2 barriers + 1 vmcnt(4) per tile.
// Round-13 change: the MODE 2 epilogue computed erff() 128x/thread (~2500
// VALU instrs, ~40% of fc1's runtime -> fc1 always slowest gemm256 while
// MODE 0 qkv with the same loop was off top-5). fast_gelu cuts that ~3x.
// ---------------------------------------------------------------------------
template <int MODE, int SPLIT>
__global__ __launch_bounds__(512)
void gemm256(const u16* __restrict__ A, const u16* __restrict__ Bt,
             const float* __restrict__ bias, const float* __restrict__ res,
             void* __restrict__ out,
             float* __restrict__ q1, float* __restrict__ q2, float* __restrict__ q3,
             int M, int N, int K, int Kc) {
    __shared__ __attribute__((aligned(16))) u16 sA[2][16384];  // 64 KiB
    __shared__ __attribute__((aligned(16))) u16 sB[2][16384];  // 64 KiB
    const int tid  = threadIdx.x;
    const int w    = tid >> 6, lane = tid & 63;
    const int wm   = w >> 2,  wn   = w & 3;
    const int q    = lane >> 4, l16 = lane & 15;
    const int w8   = w << 3,  l8   = lane >> 3;       // l8 in 0..7
    const int kch  = (lane & 7) ^ l8;                  // inverse-swizzled src chunk

    const int nwg  = gridDim.x;
    const int id   = blockIdx.x;
    const int wgid = (id & 7) * (nwg >> 3) + (id >> 3);
    int bx, by, sp;
    if (SPLIT == 1) { bx = wgid & 15; by = wgid >> 4; sp = 0; }
    else            { bx = wgid & 15; by = (wgid >> 4) & 3; sp = wgid >> 6; }

    const u16* pAs = A  + (size_t)(bx * 256 + w8 + l8) * K + kch * 8 + (size_t)sp * Kc;
    const u16* pBs = Bt + (size_t)(by * 256 + w8 + l8) * K + kch * 8 + (size_t)sp * Kc;

    const int cs0  = ((q ^ (l16 & 7)) << 4);
    const int cs1  = cs0 ^ 64;
    const int aoff = (wm * 128 + l16) * 128;
    const int boff = (wn * 64  + l16) * 128;

    f32x4 acc[8][4];
#pragma unroll
    for (int m = 0; m < 8; ++m)
#pragma unroll
        for (int n = 0; n < 4; ++n) acc[m][n] = (f32x4)0.0f;

#define GISS(P, r0, k0, SH, b_) \
    gload16((P) + (size_t)((r0) * K + (k0)), &SH[b_][((r0) + w8) * 64])

    GISS(pBs, 0, 0, sB, 0);   GISS(pBs, 64, 0, sB, 0);
    GISS(pBs, 128, 0, sB, 0); GISS(pBs, 192, 0, sB, 0);
    GISS(pAs, 0, 0, sA, 0);   GISS(pAs, 64, 0, sA, 0);
    GISS(pAs, 128, 0, sA, 0); GISS(pAs, 192, 0, sA, 0);
    GISS(pBs, 0, 64, sB, 1);  GISS(pBs, 64, 64, sB, 1);
    GISS(pBs, 128, 64, sB, 1);GISS(pBs, 192, 64, sB, 1);
    asm volatile("s_waitcnt vmcnt(4)" ::: "memory");
    __builtin_amdgcn_s_barrier();

    const int NT_ = Kc >> 6;
    for (int t = 0; t < NT_; ++t) {
        const int b  = t & 1;
        const char* bA_ = (const char*)&sA[b][0] + aoff;
        const char* bB_ = (const char*)&sB[b][0] + boff;
        const int kA = (t + 1 < NT_ ? t + 1 : t) << 6;
        const int kB = (t + 2 < NT_ ? t + 2 : t) << 6;

        if (b) { GISS(pAs, 0, kA, sA, 0); GISS(pAs, 64, kA, sA, 0);
                 GISS(pAs, 128, kA, sA, 0); GISS(pAs, 192, kA, sA, 0); }
        else   { GISS(pAs, 0, kA, sA, 1); GISS(pAs, 64, kA, sA, 1);
                 GISS(pAs, 128, kA, sA, 1); GISS(pAs, 192, kA, sA, 1); }
        bf16x8 bfr[4][2];
#pragma unroll
        for (int n = 0; n < 4; ++n) {
            bfr[n][0] = *(const bf16x8*)(bB_ + n * 2048 + cs0);
            bfr[n][1] = *(const bf16x8*)(bB_ + n * 2048 + cs1);
        }
        bf16x8 af[4][2];
#pragma unroll
        for (int m = 0; m < 4; ++m) {
            af[m][0] = *(const bf16x8*)(bA_ + m * 2048 + cs0);
            af[m][1] = *(const bf16x8*)(bA_ + m * 2048 + cs1);
        }
        __builtin_amdgcn_sched_barrier(0);
        __builtin_amdgcn_s_setprio(1);
#pragma unroll
        for (int kt = 0; kt < 2; ++kt)
#pragma unroll
            for (int m = 0; m < 4; ++m)
#pragma unroll
                for (int n = 0; n < 4; ++n)
                    acc[m][n] = mfma16(af[m][kt], bfr[n][kt], acc[m][n]);
        __builtin_amdgcn_s_setprio(0);
        __builtin_amdgcn_s_barrier();

        if (b) { GISS(pBs, 0, kB, sB, 1); GISS(pBs, 64, kB, sB, 1);
                 GISS(pBs, 128, kB, sB, 1); GISS(pBs, 192, kB, sB, 1); }
        else   { GISS(pBs, 0, kB, sB, 0); GISS(pBs, 64, kB, sB, 0);
                 GISS(pBs, 128, kB, sB, 0); GISS(pBs, 192, kB, sB, 0); }
        bf16x8 ag[4][2];
#pragma unroll
        for (int m = 0; m < 4; ++m) {
            ag[m][0] = *(const bf16x8*)(bA_ + (4 + m) * 2048 + cs0);
            ag[m][1] = *(const bf16x8*)(bA_ + (4 + m) * 2048 + cs1);
        }
        __builtin_amdgcn_sched_barrier(0);
        __builtin_amdgcn_s_setprio(1);
#pragma unroll
        for (int kt = 0; kt < 2; ++kt)
#pragma unroll
            for (int m = 0; m < 4; ++m)
#pragma unroll
                for (int n = 0; n < 4; ++n)
                    acc[4 + m][n] = mfma16(ag[m][kt], bfr[n][kt], acc[4 + m][n]);
        __builtin_amdgcn_s_setprio(0);
        asm volatile("s_waitcnt vmcnt(4)" ::: "memory");
        __builtin_amdgcn_s_barrier();
    }
#undef GISS

    float* po = nullptr;
    if (MODE == 3)
        po = sp == 0 ? (float*)out : sp == 1 ? q1 : sp == 2 ? q2 : q3;

#pragma unroll
    for (int m = 0; m < 8; ++m)
#pragma unroll
        for (int n = 0; n < 4; ++n)
#pragma unroll
            for (int r = 0; r < 4; ++r) {
                const int row = bx * 256 + wm * 128 + m * 16 + q * 4 + r;
                const int col = by * 256 + wn * 64 + n * 16 + l16;
                const size_t idx = (size_t)row * N + col;
                float v = acc[m][n][r];
                if (MODE == 0) {
                    ((u16*)out)[idx] = f2bf(v);
                } else if (MODE == 1) {
                    ((float*)out)[idx] = v + bias[col] + res[idx];
                } else if (MODE == 2) {
                    ((u16*)out)[idx] = f2bf(fast_gelu(v + bias[col]));
                } else {
                    po[idx] = v;
                }
            }
}

// ---------------------------------------------------------------------------
// Flash attention v7 (unchanged from round 9 — recovered): r4 structure +
// Q pre-scale + raw v_exp_f32 + cvtpk pack + MFMA ones-trick row-sum.
// ---------------------------------------------------------------------------
__global__ __launch_bounds__(256)
void attention3(const u16* __restrict__ qkv, const u16* __restrict__ vT,
                u16* __restrict__ o) {
    __shared__ __attribute__((aligned(16))) u16 sK[64][72];   // [key][d]
    __shared__ __attribute__((aligned(16))) u16 sV[64][72];   // [d][key]

    const int tid = threadIdx.x;
    const int lane = tid & 63, w = tid >> 6;
    const int qc = lane >> 4, l16 = lane & 15;
    const int bx = blockIdx.x;
    const int qt = bx & 15, h = (bx >> 4) & 15, b = bx >> 8;
    const int rowbase = qt * 128 + w * 32;

    const float SC = 0.18033688f;   // log2(e)/8, folded into Q once

    bf16x8 aQ[2][2];
#pragma unroll
    for (int mtq = 0; mtq < 2; ++mtq)
#pragma unroll
        for (int kd = 0; kd < 2; ++kd) {
            bf16x8 qv = *(const bf16x8*)(qkv +
                (size_t)(b * 2048 + rowbase + mtq * 16 + l16) * 3072 +
                h * 64 + kd * 32 + qc * 8);
            u32x4 pw;
#pragma unroll
            for (int i = 0; i < 4; ++i) {
                union { u32 u; float f; } lo, hi;
                lo.u = (u32)(u16)(short)qv[2 * i]     << 16;
                hi.u = (u32)(u16)(short)qv[2 * i + 1] << 16;
                pw[i] = cvtpk(lo.f * SC, hi.f * SC);
            }
            aQ[mtq][kd] = *(const bf16x8*)&pw;
        }

    f32x4 accO[2][4];
#pragma unroll
    for (int mtq = 0; mtq < 2; ++mtq)
#pragma unroll
        for (int dt = 0; dt < 4; ++dt) accO[mtq][dt] = (f32x4)0.0f;
    f32x4 accS[2];
    accS[0] = (f32x4)0.0f; accS[1] = (f32x4)0.0f;

    bf16x8 vone;
#pragma unroll
    for (int i = 0; i < 8; ++i) vone[i] = (short)0x3F80;   // bf16 1.0

    const int srr = tid >> 3;            // 0..31
    const int sc8 = (tid & 7) * 8;       // 0..56
    const u16* gK = qkv + (size_t)(b * 2048 + srr) * 3072 + 1024 + h * 64 + sc8;
    const u16* gV = vT + (size_t)(h * 64 + srr) * 4096 + b * 2048 + sc8;

    i32x4 cK[2], cV[2];
    cK[0] = *(const i32x4*)gK;
    cK[1] = *(const i32x4*)(gK + (size_t)32 * 3072);
    cV[0] = *(const i32x4*)gV;
    cV[1] = *(const i32x4*)(gV + (size_t)32 * 4096);

    const int sig_base = ((l16 >> 2) << 3) + (l16 & 3);   // q*8 + r

    for (int kc = 0; kc < 32; ++kc) {
        __syncthreads();
        *(i32x4*)&sK[srr][sc8]      = cK[0];
        *(i32x4*)&sK[srr + 32][sc8] = cK[1];
        *(i32x4*)&sV[srr][sc8]      = cV[0];
        *(i32x4*)&sV[srr + 32][sc8] = cV[1];
        const int kn = (kc + 1 < 32) ? kc + 1 : 31;
        i32x4 nK[2], nV[2];
        nK[0] = *(const i32x4*)(gK + (size_t)kn * 64 * 3072);
        nK[1] = *(const i32x4*)(gK + ((size_t)kn * 64 + 32) * 3072);
        nV[0] = *(const i32x4*)(gV + kn * 64);
        nV[1] = *(const i32x4*)(gV + (size_t)32 * 4096 + kn * 64);
        __syncthreads();

        bf16x8 kf[4][2];
#pragma unroll
        for (int mk = 0; mk < 4; ++mk) {
            const int krow = ((mk & 1) << 5) + ((mk >> 1) << 2) + sig_base;
            kf[mk][0] = *(const bf16x8*)&sK[krow][qc * 8];
            kf[mk][1] = *(const bf16x8*)&sK[krow][32 + qc * 8];
        }

        f32x4 s[2][4];
#pragma unroll
        for (int mtq = 0; mtq < 2; ++mtq)
#pragma unroll
            for (int mk = 0; mk < 4; ++mk) {
                f32x4 z = (f32x4)0.0f;
                z = mfma16(kf[mk][0], aQ[mtq][0], z);
                z = mfma16(kf[mk][1], aQ[mtq][1], z);
                s[mtq][mk] = z;
            }

        bf16x8 pf[2][2];
#pragma unroll
        for (int mtq = 0; mtq < 2; ++mtq) {
#pragma unroll
            for (int mk = 0; mk < 4; ++mk)
#pragma unroll
                for (int r = 0; r < 4; ++r)
                    s[mtq][mk][r] = __builtin_amdgcn_exp2f(s[mtq][mk][r]);
#pragma unroll
            for (int kt = 0; kt < 2; ++kt) {
                u32x4 pw;
                pw[0] = cvtpk(s[mtq][kt][0],     s[mtq][kt][1]);
                pw[1] = cvtpk(s[mtq][kt][2],     s[mtq][kt][3]);
                pw[2] = cvtpk(s[mtq][2 + kt][0], s[mtq][2 + kt][1]);
                pw[3] = cvtpk(s[mtq][2 + kt][2], s[mtq][2 + kt][3]);
                pf[mtq][kt] = *(const bf16x8*)&pw;
            }
        }

#pragma unroll
        for (int kt = 0; kt < 2; ++kt) {
#pragma unroll
            for (int dt = 0; dt < 4; ++dt) {
                bf16x8 vf = *(const bf16x8*)&sV[dt * 16 + l16][kt * 32 + qc * 8];
#pragma unroll
                for (int mtq = 0; mtq < 2; ++mtq)
                    accO[mtq][dt] = mfma16(pf[mtq][kt], vf, accO[mtq][dt]);
            }
#pragma unroll
            for (int mtq = 0; mtq < 2; ++mtq)
                accS[mtq] = mfma16(pf[mtq][kt], vone, accS[mtq]);
        }

        cK[0] = nK[0]; cK[1] = nK[1];
        cV[0] = nV[0]; cV[1] = nV[1];
    }

#pragma unroll
    for (int mtq = 0; mtq < 2; ++mtq)
#pragma unroll
        for (int r = 0; r < 4; ++r) {
            const float inv = 1.0f / accS[mtq][r];
            const size_t tok = (size_t)b * 2048 + rowbase + mtq * 16 + qc * 4 + r;
#pragma unroll
            for (int dt = 0; dt < 4; ++dt)
                o[tok * 1024 + h * 64 + dt * 16 + l16] = f2bf(accO[mtq][dt][r] * inv);
        }
}

// ---------------------------------------------------------------------------
extern "C" void kernel_launch(void* const* d_in, const int* in_sizes, int n_in,
                              void* d_out, int out_size, void* d_ws, size_t ws_size,
                              hipStream_t stream) {
    const float* x      = (const float*)d_in[0];
    const float* ln1_g  = (const float*)d_in[1];
    const float* ln1_b  = (const float*)d_in[2];
    const float* w_qkv  = (const float*)d_in[3];
    const float* w_proj = (const float*)d_in[4];
    const float* b_proj = (const float*)d_in[5];
    const float* ln2_g  = (const float*)d_in[6];
    const float* ln2_b  = (const float*)d_in[7];
    const float* w_fc1  = (const float*)d_in[8];
    const float* b_fc1  = (const float*)d_in[9];
    const float* w_fc2  = (const float*)d_in[10];
    const float* b_fc2  = (const float*)d_in[11];
    float* out = (float*)d_out;

    // workspace layout (bytes); total ~104 MB
    char* ws = (char*)d_ws;
    u16*   wqkvT  = (u16*)(ws + 0);           //  6 MB  [3072][1024]
    u16*   wprojT = (u16*)(ws + 6291456);     //  2 MB  [1024][1024]
    u16*   wfc1T  = (u16*)(ws + 8388608);     //  8 MB  [4096][1024]
    u16*   wfc2T  = (u16*)(ws + 16777216);    //  8 MB  [1024][4096]
    u16*   hA     = (u16*)(ws + 25165824);    //  8 MB  ln1 out; reused for attn out
    u16*   qkv    = (u16*)(ws + 33554432);    // 24 MB  [4096][3072]; reused for h2
    float* x1     = (float*)(ws + 58720256);  // 16 MB  [4096][1024] fp32
    u16*   gbuf   = (u16*)(ws + 75497472);    // 32 MB  [4096][4096] gelu out
    u16*   vT     = (u16*)(ws + 75497472);    //  8 MB  aliases gbuf (dead before fc1)
    // fc2 split-K fp32 partials (regions dead by fc2 time):
    float* p1     = (float*)(ws + 0);         // 16 MB over wqkvT/wprojT/wfc1T
    float* p2     = (float*)(ws + 25165824);  // 16 MB over hA + qkv head
    float* p3     = (float*)(ws + 41943040);  // 16 MB over qkv tail (ends at x1)

    dim3 blk(256);
    transpose_all<<<12288, blk, 0, stream>>>(w_qkv, wqkvT, w_proj, wprojT,
                                             w_fc1, wfc1T, w_fc2, wfc2T);

    ln_kernel<<<4096, blk, 0, stream>>>(x, ln1_g, ln1_b, hA);
    gemm256<0, 1><<<192, dim3(512), 0, stream>>>(hA, wqkvT, nullptr, nullptr, qkv,
                                                 nullptr, nullptr, nullptr, 4096, 3072, 1024, 1024);
    vtrans<<<dim3(64, 16), blk, 0, stream>>>(qkv, vT);
    attention3<<<512, blk, 0, stream>>>(qkv, vT, hA);
    gemm64<1, 4, 1, 2, 4, 2><<<512, blk, 0, stream>>>(hA, wprojT, b_proj, x, x1, 4096, 1024, 1024);

    u16* h2 = qkv;  // qkv dead after attention
    ln_kernel<<<4096, blk, 0, stream>>>(x1, ln2_g, ln2_b, h2);
    gemm256<2, 1><<<256, dim3(512), 0, stream>>>(h2, wfc1T, b_fc1, nullptr, gbuf,
                                                 nullptr, nullptr, nullptr, 4096, 4096, 1024, 1024);
    // fc2: split-K x4 (Kc=1024), raw fp32 partials; p0 = out
    gemm256<3, 4><<<256, dim3(512), 0, stream>>>(gbuf, wfc2T, nullptr, nullptr, out,
                                                 p1, p2, p3, 4096, 1024, 4096, 1024);
    reduce4<<<4096, blk, 0, stream>>>(p1, p2, p3, b_fc2, x1, out);
}

// Round 14
// 335.978 us; speedup vs baseline: 1.1078x; 1.0181x over previous
//
#include <hip/hip_runtime.h>
#include <hip/hip_bf16.h>

typedef unsigned short u16;
typedef unsigned int u32;
typedef __attribute__((ext_vector_type(8))) short bf16x8;
typedef __attribute__((ext_vector_type(4))) float f32x4;
typedef __attribute__((ext_vector_type(4))) int   i32x4;
typedef __attribute__((ext_vector_type(4))) float fvec4;
typedef __attribute__((ext_vector_type(4))) unsigned int u32x4;

__device__ inline u16 f2bf(float f) {
    union { float f; unsigned u; } v; v.f = f;
    unsigned r = v.u + 0x7fffu + ((v.u >> 16) & 1u);
    return (u16)(r >> 16);
}

// packed f32x2 -> bf16x2 (RNE), dst.lo = bf16(lo), dst.hi = bf16(hi)
__device__ inline u32 cvtpk(float lo, float hi) {
    u32 r;
    asm("v_cvt_pk_bf16_f32 %0, %1, %2" : "=v"(r) : "v"(lo), "v"(hi));
    return r;
}

// fast GELU (tanh form): t * sigmoid(1.5957691*(t + 0.044715 t^3))
//  = t * rcp(1 + exp2(-2.3021876*(t + 0.044715 t^3)))
// ~8 VALU ops w/ hw v_exp+v_rcp vs ~25 for OCML erff; |err vs exact-erf
// GELU| < 1e-3 absolute, below bf16 output quantization. (r13: fc1 -10us)
__device__ inline float fast_gelu(float t) {
    float w = t + 0.044715f * t * t * t;
    float e = __builtin_amdgcn_exp2f(-2.3021876f * w);
    return t * __builtin_amdgcn_rcpf(1.0f + e);
}

__device__ inline f32x4 mfma16(bf16x8 a, bf16x8 b, f32x4 c) {
    return __builtin_amdgcn_mfma_f32_16x16x32_bf16(a, b, c, 0, 0, 0);
}

// async global->LDS, 16B per lane. lds ptr must be wave-uniform; HW adds lane*16.
__device__ inline void gload16(const void* g, void* l) {
    __builtin_amdgcn_global_load_lds(
        (const __attribute__((address_space(1))) unsigned int*)g,
        (__attribute__((address_space(3))) unsigned int*)l, 16, 0, 0);
}

// ---------------------------------------------------------------------------
// All-weights transpose + cast in ONE launch: 4 segments of 32x32 tiles.
// in[K][N] fp32 -> out[N][K] bf16.
// ---------------------------------------------------------------------------
__global__ __launch_bounds__(256)
void transpose_all(const float* __restrict__ w0, u16* __restrict__ o0,   // qkv  K=1024 N=3072
                   const float* __restrict__ w1, u16* __restrict__ o1,   // proj K=1024 N=1024
                   const float* __restrict__ w2, u16* __restrict__ o2,   // fc1  K=1024 N=4096
                   const float* __restrict__ w3, u16* __restrict__ o3) { // fc2  K=4096 N=1024
    __shared__ float tile[32][33];
    int b = blockIdx.x;
    const float* in; u16* out; int K, N, local;
    if (b < 3072)      { in = w0; out = o0; K = 1024; N = 3072; local = b; }
    else if (b < 4096) { in = w1; out = o1; K = 1024; N = 1024; local = b - 3072; }
    else if (b < 8192) { in = w2; out = o2; K = 1024; N = 4096; local = b - 4096; }
    else               { in = w3; out = o3; K = 4096; N = 1024; local = b - 8192; }
    const int nx = N >> 5;
    const int n0 = (local % nx) * 32, k0 = (local / nx) * 32;
    const int x = threadIdx.x & 31, y = threadIdx.x >> 5;
    for (int i = 0; i < 4; ++i)
        tile[y + i * 8][x] = in[(size_t)(k0 + y + i * 8) * N + n0 + x];
    __syncthreads();
    for (int i = 0; i < 4; ++i) {
        int r = y + i * 8;
        out[(size_t)(n0 + r) * K + k0 + x] = f2bf(tile[x][r]);
    }
}

// ---------------------------------------------------------------------------
// V transpose (bf16): qkv[4096][3072] (V = cols 2048..3071) -> vT[1024][4096]
// ---------------------------------------------------------------------------
__global__ __launch_bounds__(256)
void vtrans(const u16* __restrict__ qkv, u16* __restrict__ vT) {
    __shared__ u32 tl[64][33];
    const int t0 = blockIdx.x * 64, f0 = blockIdx.y * 64;
    const int a = threadIdx.x & 31, yy = threadIdx.x >> 5;
    for (int i = 0; i < 8; ++i) {
        int t = yy + i * 8;
        tl[t][a] = *(const u32*)(qkv + (size_t)(t0 + t) * 3072 + 2048 + f0 + a * 2);
    }
    __syncthreads();
    for (int i = 0; i < 8; ++i) {
        int f = yy + i * 8;
        u32 lo = tl[2 * a][f >> 1], hi = tl[2 * a + 1][f >> 1];
        u32 r = (f & 1) ? ((lo >> 16) | (hi & 0xffff0000u))
                        : ((lo & 0xffffu) | (hi << 16));
        *(u32*)(vT + (size_t)(f0 + f) * 4096 + t0 + 2 * a) = r;
    }
}

// ---------------------------------------------------------------------------
// LayerNorm: x[rows][1024] fp32 -> out bf16. One block (256 thr) per row.
// ---------------------------------------------------------------------------
__global__ __launch_bounds__(256)
void ln_kernel(const float* __restrict__ x, const float* __restrict__ g,
               const float* __restrict__ bvec, u16* __restrict__ out) {
    __shared__ float red[2][4];
    const int row = blockIdx.x, tid = threadIdx.x;
    const float* xr = x + (size_t)row * 1024;
    fvec4 v = *(const fvec4*)(xr + tid * 4);
    float s  = v[0] + v[1] + v[2] + v[3];
    float s2 = v[0]*v[0] + v[1]*v[1] + v[2]*v[2] + v[3]*v[3];
    for (int off = 1; off < 64; off <<= 1) {
        s  += __shfl_xor(s,  off);
        s2 += __shfl_xor(s2, off);
    }
    const int w = tid >> 6;
    if ((tid & 63) == 0) { red[0][w] = s; red[1][w] = s2; }
    __syncthreads();
    s  = red[0][0] + red[0][1] + red[0][2] + red[0][3];
    s2 = red[1][0] + red[1][1] + red[1][2] + red[1][3];
    const float mu  = s * (1.0f / 1024.0f);
    const float var = s2 * (1.0f / 1024.0f) - mu * mu;
    const float rstd = rsqrtf(var + 1e-5f);
    fvec4 gv = *(const fvec4*)(g + tid * 4);
    fvec4 bv = *(const fvec4*)(bvec + tid * 4);
    u16 o4[4];
    for (int i = 0; i < 4; ++i)
        o4[i] = f2bf((v[i] - mu) * rstd * gv[i] + bv[i]);
    u32 lo = (u32)o4[0] | ((u32)o4[1] << 16);
    u32 hi = (u32)o4[2] | ((u32)o4[3] << 16);
    u32* dst = (u32*)(out + (size_t)row * 1024 + tid * 4);
    dst[0] = lo; dst[1] = hi;
}

// ---------------------------------------------------------------------------
// reduce4: out = p0+p1+p2+p3 + bias[col] + res. One block per row (1024 f32).
// ---------------------------------------------------------------------------
__global__ __launch_bounds__(256)
void reduce4(const float* __restrict__ p1, const float* __restrict__ p2,
             const float* __restrict__ p3, const float* __restrict__ bias,
             const float* __restrict__ res, float* __restrict__ out) {
    const size_t base = (size_t)blockIdx.x * 1024 + threadIdx.x * 4;
    fvec4 a = *(const fvec4*)(out + base);     // p0 aliases out
    fvec4 b = *(const fvec4*)(p1 + base);
    fvec4 c = *(const fvec4*)(p2 + base);
    fvec4 d = *(const fvec4*)(p3 + base);
    fvec4 r = *(const fvec4*)(res + base);
    fvec4 bi = *(const fvec4*)(bias + threadIdx.x * 4);
    fvec4 o;
#pragma unroll
    for (int i = 0; i < 4; ++i) o[i] = ((a[i] + b[i]) + (c[i] + d[i])) + bi[i] + r[i];
    *(fvec4*)(out + base) = o;
}

// ---------------------------------------------------------------------------
// gemm64: BK=64 single-buffered 128-wide-tile GEMM (kept for proj).
// ---------------------------------------------------------------------------
template <int MODE, int WM, int WN, int MT, int NT, int NYP>
__global__ __launch_bounds__(256)
void gemm64(const u16* __restrict__ A, const u16* __restrict__ Bt,
            const float* __restrict__ bias, const float* __restrict__ res,
            void* __restrict__ out, int M, int N, int K) {
    constexpr int TM = WM * MT * 16;
    constexpr int TN = WN * NT * 16;
    constexpr int AJ = TM / 64;
    constexpr int BJ = TN / 64;
    static_assert(TM == 128, "swizzle assumes 32 M-tiles");
    __shared__ __attribute__((aligned(16))) u16 sA[2 * TM * 32];  // [kt][row][32]
    __shared__ __attribute__((aligned(16))) u16 sB[2 * TN * 32];
    const int id = blockIdx.x;
    const int j  = id >> 3;
    const int by = (id & 7) * NYP + (j >> 5);
    const int bx = j & 31;
    const int tid = threadIdx.x;
    const int lane = tid & 63, w = tid >> 6;
    const int wm = w / WN, wn = w % WN;
    const int q = lane >> 4, l16 = lane & 15;

    f32x4 acc[MT][NT];
#pragma unroll
    for (int i = 0; i < MT; ++i)
#pragma unroll
        for (int jj = 0; jj < NT; ++jj) acc[i][jj] = (f32x4)0.0f;

    const int sr = lane >> 2;            // 0..15
    const int kc = (lane & 3) * 8;       // 0,8,16,24
    const u16* gA[AJ];
    const u16* gB[BJ];
#pragma unroll
    for (int jj = 0; jj < AJ; ++jj)
        gA[jj] = A + (size_t)(bx * TM + (jj * 4 + w) * 16 + sr) * K + kc;
#pragma unroll
    for (int jj = 0; jj < BJ; ++jj)
        gB[jj] = Bt + (size_t)(by * TN + (jj * 4 + w) * 16 + sr) * K + kc;

    for (int k0 = 0; k0 < K; k0 += 64) {
#pragma unroll
        for (int kt = 0; kt < 2; ++kt) {
#pragma unroll
            for (int jj = 0; jj < AJ; ++jj)
                gload16(gA[jj] + k0 + kt * 32, &sA[kt * TM * 32 + (jj * 4 + w) * 512]);
#pragma unroll
            for (int jj = 0; jj < BJ; ++jj)
                gload16(gB[jj] + k0 + kt * 32, &sB[kt * TN * 32 + (jj * 4 + w) * 512]);
        }
        __syncthreads();
#pragma unroll
        for (int kt = 0; kt < 2; ++kt) {
            bf16x8 af[MT], bf[NT];
#pragma unroll
            for (int mt = 0; mt < MT; ++mt)
                af[mt] = *(const bf16x8*)&sA[kt * TM * 32 +
                         (wm * MT * 16 + mt * 16 + l16) * 32 + q * 8];
#pragma unroll
            for (int nt = 0; nt < NT; ++nt)
                bf[nt] = *(const bf16x8*)&sB[kt * TN * 32 +
                         (wn * NT * 16 + nt * 16 + l16) * 32 + q * 8];
#pragma unroll
            for (int mt = 0; mt < MT; ++mt)
#pragma unroll
                for (int nt = 0; nt < NT; ++nt)
                    acc[mt][nt] = mfma16(af[mt], bf[nt], acc[mt][nt]);
        }
        __syncthreads();
    }

#pragma unroll
    for (int mt = 0; mt < MT; ++mt)
#pragma unroll
        for (int nt = 0; nt < NT; ++nt)
#pragma unroll
            for (int r = 0; r < 4; ++r) {
                const int row = bx * TM + wm * MT * 16 + mt * 16 + q * 4 + r;
                const int col = by * TN + wn * NT * 16 + nt * 16 + l16;
                const size_t idx = (size_t)row * N + col;
                float v = acc[mt][nt][r];
                if (MODE == 0) {
                    ((u16*)out)[idx] = f2bf(v);
                } else if (MODE == 1) {
                    ((float*)out)[idx] = v + bias[col] + res[idx];
                } else {
                    ((u16*)out)[idx] = f2bf(fast_gelu(v + bias[col]));
                }
            }
}

// ---------------------------------------------------------------------------
// gemm256 v4 (r13-verified: loop pinned, fast_gelu epilogue):
// 256x256 tile, BK=64, 8 waves, double-buffered LDS, two super-phases per
// K-tile, each {GISS first -> ds_reads -> sched_barrier(0) -> setprio+MFMA},
// 2 barriers + 1 vmcnt(4) per tile.
// ---------------------------------------------------------------------------
template <int MODE, int SPLIT>
__global__ __launch_bounds__(512)
void gemm256(const u16* __restrict__ A, const u16* __restrict__ Bt,
             const float* __restrict__ bias, const float* __restrict__ res,
             void* __restrict__ out,
             float* __restrict__ q1, float* __restrict__ q2, float* __restrict__ q3,
             int M, int N, int K, int Kc) {
    __shared__ __attribute__((aligned(16))) u16 sA[2][16384];  // 64 KiB
    __shared__ __attribute__((aligned(16))) u16 sB[2][16384];  // 64 KiB
    const int tid  = threadIdx.x;
    const int w    = tid >> 6, lane = tid & 63;
    const int wm   = w >> 2,  wn   = w & 3;
    const int q    = lane >> 4, l16 = lane & 15;
    const int w8   = w << 3,  l8   = lane >> 3;       // l8 in 0..7
    const int kch  = (lane & 7) ^ l8;                  // inverse-swizzled src chunk

    const int nwg  = gridDim.x;
    const int id   = blockIdx.x;
    const int wgid = (id & 7) * (nwg >> 3) + (id >> 3);
    int bx, by, sp;
    if (SPLIT == 1) { bx = wgid & 15; by = wgid >> 4; sp = 0; }
    else            { bx = wgid & 15; by = (wgid >> 4) & 3; sp = wgid >> 6; }

    const u16* pAs = A  + (size_t)(bx * 256 + w8 + l8) * K + kch * 8 + (size_t)sp * Kc;
    const u16* pBs = Bt + (size_t)(by * 256 + w8 + l8) * K + kch * 8 + (size_t)sp * Kc;

    const int cs0  = ((q ^ (l16 & 7)) << 4);
    const int cs1  = cs0 ^ 64;
    const int aoff = (wm * 128 + l16) * 128;
    const int boff = (wn * 64  + l16) * 128;

    f32x4 acc[8][4];
#pragma unroll
    for (int m = 0; m < 8; ++m)
#pragma unroll
        for (int n = 0; n < 4; ++n) acc[m][n] = (f32x4)0.0f;

#define GISS(P, r0, k0, SH, b_) \
    gload16((P) + (size_t)((r0) * K + (k0)), &SH[b_][((r0) + w8) * 64])

    GISS(pBs, 0, 0, sB, 0);   GISS(pBs, 64, 0, sB, 0);
    GISS(pBs, 128, 0, sB, 0); GISS(pBs, 192, 0, sB, 0);
    GISS(pAs, 0, 0, sA, 0);   GISS(pAs, 64, 0, sA, 0);
    GISS(pAs, 128, 0, sA, 0); GISS(pAs, 192, 0, sA, 0);
    GISS(pBs, 0, 64, sB, 1);  GISS(pBs, 64, 64, sB, 1);
    GISS(pBs, 128, 64, sB, 1);GISS(pBs, 192, 64, sB, 1);
    asm volatile("s_waitcnt vmcnt(4)" ::: "memory");
    __builtin_amdgcn_s_barrier();

    const int NT_ = Kc >> 6;
    for (int t = 0; t < NT_; ++t) {
        const int b  = t & 1;
        const char* bA_ = (const char*)&sA[b][0] + aoff;
        const char* bB_ = (const char*)&sB[b][0] + boff;
        const int kA = (t + 1 < NT_ ? t + 1 : t) << 6;
        const int kB = (t + 2 < NT_ ? t + 2 : t) << 6;

        if (b) { GISS(pAs, 0, kA, sA, 0); GISS(pAs, 64, kA, sA, 0);
                 GISS(pAs, 128, kA, sA, 0); GISS(pAs, 192, kA, sA, 0); }
        else   { GISS(pAs, 0, kA, sA, 1); GISS(pAs, 64, kA, sA, 1);
                 GISS(pAs, 128, kA, sA, 1); GISS(pAs, 192, kA, sA, 1); }
        bf16x8 bfr[4][2];
#pragma unroll
        for (int n = 0; n < 4; ++n) {
            bfr[n][0] = *(const bf16x8*)(bB_ + n * 2048 + cs0);
            bfr[n][1] = *(const bf16x8*)(bB_ + n * 2048 + cs1);
        }
        bf16x8 af[4][2];
#pragma unroll
        for (int m = 0; m < 4; ++m) {
            af[m][0] = *(const bf16x8*)(bA_ + m * 2048 + cs0);
            af[m][1] = *(const bf16x8*)(bA_ + m * 2048 + cs1);
        }
        __builtin_amdgcn_sched_barrier(0);
        __builtin_amdgcn_s_setprio(1);
#pragma unroll
        for (int kt = 0; kt < 2; ++kt)
#pragma unroll
            for (int m = 0; m < 4; ++m)
#pragma unroll
                for (int n = 0; n < 4; ++n)
                    acc[m][n] = mfma16(af[m][kt], bfr[n][kt], acc[m][n]);
        __builtin_amdgcn_s_setprio(0);
        __builtin_amdgcn_s_barrier();

        if (b) { GISS(pBs, 0, kB, sB, 1); GISS(pBs, 64, kB, sB, 1);
                 GISS(pBs, 128, kB, sB, 1); GISS(pBs, 192, kB, sB, 1); }
        else   { GISS(pBs, 0, kB, sB, 0); GISS(pBs, 64, kB, sB, 0);
                 GISS(pBs, 128, kB, sB, 0); GISS(pBs, 192, kB, sB, 0); }
        bf16x8 ag[4][2];
#pragma unroll
        for (int m = 0; m < 4; ++m) {
            ag[m][0] = *(const bf16x8*)(bA_ + (4 + m) * 2048 + cs0);
            ag[m][1] = *(const bf16x8*)(bA_ + (4 + m) * 2048 + cs1);
        }
        __builtin_amdgcn_sched_barrier(0);
        __builtin_amdgcn_s_setprio(1);
#pragma unroll
        for (int kt = 0; kt < 2; ++kt)
#pragma unroll
            for (int m = 0; m < 4; ++m)
#pragma unroll
                for (int n = 0; n < 4; ++n)
                    acc[4 + m][n] = mfma16(ag[m][kt], bfr[n][kt], acc[4 + m][n]);
        __builtin_amdgcn_s_setprio(0);
        asm volatile("s_waitcnt vmcnt(4)" ::: "memory");
        __builtin_amdgcn_s_barrier();
    }
#undef GISS

    float* po = nullptr;
    if (MODE == 3)
        po = sp == 0 ? (float*)out : sp == 1 ? q1 : sp == 2 ? q2 : q3;

#pragma unroll
    for (int m = 0; m < 8; ++m)
#pragma unroll
        for (int n = 0; n < 4; ++n)
#pragma unroll
            for (int r = 0; r < 4; ++r) {
                const int row = bx * 256 + wm * 128 + m * 16 + q * 4 + r;
                const int col = by * 256 + wn * 64 + n * 16 + l16;
                const size_t idx = (size_t)row * N + col;
                float v = acc[m][n][r];
                if (MODE == 0) {
                    ((u16*)out)[idx] = f2bf(v);
                } else if (MODE == 1) {
                    ((float*)out)[idx] = v + bias[col] + res[idx];
                } else if (MODE == 2) {
                    ((u16*)out)[idx] = f2bf(fast_gelu(v + bias[col]));
                } else {
                    po[idx] = v;
                }
            }
}

// ---------------------------------------------------------------------------
// Flash attention v8 = r13's v7 + T5 s_setprio around the QK^T and PV MFMA
// clusters (m191: +4-7% on attn with cross-block wave diversity; 2 blocks/CU
// here, the co-resident block's waves stage while this block's waves MFMA).
// Everything else byte-identical to the r13 session-best.
// ---------------------------------------------------------------------------
__global__ __launch_bounds__(256)
void attention3(const u16* __restrict__ qkv, const u16* __restrict__ vT,
                u16* __restrict__ o) {
    __shared__ __attribute__((aligned(16))) u16 sK[64][72];   // [key][d]
    __shared__ __attribute__((aligned(16))) u16 sV[64][72];   // [d][key]

    const int tid = threadIdx.x;
    const int lane = tid & 63, w = tid >> 6;
    const int qc = lane >> 4, l16 = lane & 15;
    const int bx = blockIdx.x;
    const int qt = bx & 15, h = (bx >> 4) & 15, b = bx >> 8;
    const int rowbase = qt * 128 + w * 32;

    const float SC = 0.18033688f;   // log2(e)/8, folded into Q once

    bf16x8 aQ[2][2];
#pragma unroll
    for (int mtq = 0; mtq < 2; ++mtq)
#pragma unroll
        for (int kd = 0; kd < 2; ++kd) {
            bf16x8 qv = *(const bf16x8*)(qkv +
                (size_t)(b * 2048 + rowbase + mtq * 16 + l16) * 3072 +
                h * 64 + kd * 32 + qc * 8);
            u32x4 pw;
#pragma unroll
            for (int i = 0; i < 4; ++i) {
                union { u32 u; float f; } lo, hi;
                lo.u = (u32)(u16)(short)qv[2 * i]     << 16;
                hi.u = (u32)(u16)(short)qv[2 * i + 1] << 16;
                pw[i] = cvtpk(lo.f * SC, hi.f * SC);
            }
            aQ[mtq][kd] = *(const bf16x8*)&pw;
        }

    f32x4 accO[2][4];
#pragma unroll
    for (int mtq = 0; mtq < 2; ++mtq)
#pragma unroll
        for (int dt = 0; dt < 4; ++dt) accO[mtq][dt] = (f32x4)0.0f;
    f32x4 accS[2];
    accS[0] = (f32x4)0.0f; accS[1] = (f32x4)0.0f;

    bf16x8 vone;
#pragma unroll
    for (int i = 0; i < 8; ++i) vone[i] = (short)0x3F80;   // bf16 1.0

    const int srr = tid >> 3;            // 0..31
    const int sc8 = (tid & 7) * 8;       // 0..56
    const u16* gK = qkv + (size_t)(b * 2048 + srr) * 3072 + 1024 + h * 64 + sc8;
    const u16* gV = vT + (size_t)(h * 64 + srr) * 4096 + b * 2048 + sc8;

    i32x4 cK[2], cV[2];
    cK[0] = *(const i32x4*)gK;
    cK[1] = *(const i32x4*)(gK + (size_t)32 * 3072);
    cV[0] = *(const i32x4*)gV;
    cV[1] = *(const i32x4*)(gV + (size_t)32 * 4096);

    const int sig_base = ((l16 >> 2) << 3) + (l16 & 3);   // q*8 + r

    for (int kc = 0; kc < 32; ++kc) {
        __syncthreads();
        *(i32x4*)&sK[srr][sc8]      = cK[0];
        *(i32x4*)&sK[srr + 32][sc8] = cK[1];
        *(i32x4*)&sV[srr][sc8]      = cV[0];
        *(i32x4*)&sV[srr + 32][sc8] = cV[1];
        const int kn = (kc + 1 < 32) ? kc + 1 : 31;
        i32x4 nK[2], nV[2];
        nK[0] = *(const i32x4*)(gK + (size_t)kn * 64 * 3072);
        nK[1] = *(const i32x4*)(gK + ((size_t)kn * 64 + 32) * 3072);
        nV[0] = *(const i32x4*)(gV + kn * 64);
        nV[1] = *(const i32x4*)(gV + (size_t)32 * 4096 + kn * 64);
        __syncthreads();

        bf16x8 kf[4][2];
#pragma unroll
        for (int mk = 0; mk < 4; ++mk) {
            const int krow = ((mk & 1) << 5) + ((mk >> 1) << 2) + sig_base;
            kf[mk][0] = *(const bf16x8*)&sK[krow][qc * 8];
            kf[mk][1] = *(const bf16x8*)&sK[krow][32 + qc * 8];
        }

        f32x4 s[2][4];
        __builtin_amdgcn_s_setprio(1);
#pragma unroll
        for (int mtq = 0; mtq < 2; ++mtq)
#pragma unroll
            for (int mk = 0; mk < 4; ++mk) {
                f32x4 z = (f32x4)0.0f;
                z = mfma16(kf[mk][0], aQ[mtq][0], z);
                z = mfma16(kf[mk][1], aQ[mtq][1], z);
                s[mtq][mk] = z;
            }
        __builtin_amdgcn_s_setprio(0);

        bf16x8 pf[2][2];
#pragma unroll
        for (int mtq = 0; mtq < 2; ++mtq) {
#pragma unroll
            for (int mk = 0; mk < 4; ++mk)
#pragma unroll
                for (int r = 0; r < 4; ++r)
                    s[mtq][mk][r] = __builtin_amdgcn_exp2f(s[mtq][mk][r]);
#pragma unroll
            for (int kt = 0; kt < 2; ++kt) {
                u32x4 pw;
                pw[0] = cvtpk(s[mtq][kt][0],     s[mtq][kt][1]);
                pw[1] = cvtpk(s[mtq][kt][2],     s[mtq][kt][3]);
                pw[2] = cvtpk(s[mtq][2 + kt][0], s[mtq][2 + kt][1]);
                pw[3] = cvtpk(s[mtq][2 + kt][2], s[mtq][2 + kt][3]);
                pf[mtq][kt] = *(const bf16x8*)&pw;
            }
        }

        __builtin_amdgcn_s_setprio(1);
#pragma unroll
        for (int kt = 0; kt < 2; ++kt) {
#pragma unroll
            for (int dt = 0; dt < 4; ++dt) {
                bf16x8 vf = *(const bf16x8*)&sV[dt * 16 + l16][kt * 32 + qc * 8];
#pragma unroll
                for (int mtq = 0; mtq < 2; ++mtq)
                    accO[mtq][dt] = mfma16(pf[mtq][kt], vf, accO[mtq][dt]);
            }
#pragma unroll
            for (int mtq = 0; mtq < 2; ++mtq)
                accS[mtq] = mfma16(pf[mtq][kt], vone, accS[mtq]);
        }
        __builtin_amdgcn_s_setprio(0);

        cK[0] = nK[0]; cK[1] = nK[1];
        cV[0] = nV[0]; cV[1] = nV[1];
    }

#pragma unroll
    for (int mtq = 0; mtq < 2; ++mtq)
#pragma unroll
        for (int r = 0; r < 4; ++r) {
            const float inv = 1.0f / accS[mtq][r];
            const size_t tok = (size_t)b * 2048 + rowbase + mtq * 16 + qc * 4 + r;
#pragma unroll
            for (int dt = 0; dt < 4; ++dt)
                o[tok * 1024 + h * 64 + dt * 16 + l16] = f2bf(accO[mtq][dt][r] * inv);
        }
}

// ---------------------------------------------------------------------------
extern "C" void kernel_launch(void* const* d_in, const int* in_sizes, int n_in,
                              void* d_out, int out_size, void* d_ws, size_t ws_size,
                              hipStream_t stream) {
    const float* x      = (const float*)d_in[0];
    const float* ln1_g  = (const float*)d_in[1];
    const float* ln1_b  = (const float*)d_in[2];
    const float* w_qkv  = (const float*)d_in[3];
    const float* w_proj = (const float*)d_in[4];
    const float* b_proj = (const float*)d_in[5];
    const float* ln2_g  = (const float*)d_in[6];
    const float* ln2_b  = (const float*)d_in[7];
    const float* w_fc1  = (const float*)d_in[8];
    const float* b_fc1  = (const float*)d_in[9];
    const float* w_fc2  = (const float*)d_in[10];
    const float* b_fc2  = (const float*)d_in[11];
    float* out = (float*)d_out;

    // workspace layout (bytes); total ~104 MB
    char* ws = (char*)d_ws;
    u16*   wqkvT  = (u16*)(ws + 0);           //  6 MB  [3072][1024]
    u16*   wprojT = (u16*)(ws + 6291456);     //  2 MB  [1024][1024]
    u16*   wfc1T  = (u16*)(ws + 8388608);     //  8 MB  [4096][1024]
    u16*   wfc2T  = (u16*)(ws + 16777216);    //  8 MB  [1024][4096]
    u16*   hA     = (u16*)(ws + 25165824);    //  8 MB  ln1 out; reused for attn out
    u16*   qkv    = (u16*)(ws + 33554432);    // 24 MB  [4096][3072]; reused for h2
    float* x1     = (float*)(ws + 58720256);  // 16 MB  [4096][1024] fp32
    u16*   gbuf   = (u16*)(ws + 75497472);    // 32 MB  [4096][4096] gelu out
    u16*   vT     = (u16*)(ws + 75497472);    //  8 MB  aliases gbuf (dead before fc1)
    // fc2 split-K fp32 partials (regions dead by fc2 time):
    float* p1     = (float*)(ws + 0);         // 16 MB over wqkvT/wprojT/wfc1T
    float* p2     = (float*)(ws + 25165824);  // 16 MB over hA + qkv head
    float* p3     = (float*)(ws + 41943040);  // 16 MB over qkv tail (ends at x1)

    dim3 blk(256);
    transpose_all<<<12288, blk, 0, stream>>>(w_qkv, wqkvT, w_proj, wprojT,
                                             w_fc1, wfc1T, w_fc2, wfc2T);

    ln_kernel<<<4096, blk, 0, stream>>>(x, ln1_g, ln1_b, hA);
    gemm256<0, 1><<<192, dim3(512), 0, stream>>>(hA, wqkvT, nullptr, nullptr, qkv,
                                                 nullptr, nullptr, nullptr, 4096, 3072, 1024, 1024);
    vtrans<<<dim3(64, 16), blk, 0, stream>>>(qkv, vT);
    attention3<<<512, blk, 0, stream>>>(qkv, vT, hA);
    gemm64<1, 4, 1, 2, 4, 2><<<512, blk, 0, stream>>>(hA, wprojT, b_proj, x, x1, 4096, 1024, 1024);

    u16* h2 = qkv;  // qkv dead after attention
    ln_kernel<<<4096, blk, 0, stream>>>(x1, ln2_g, ln2_b, h2);
    gemm256<2, 1><<<256, dim3(512), 0, stream>>>(h2, wfc1T, b_fc1, nullptr, gbuf,
                                                 nullptr, nullptr, nullptr, 4096, 4096, 1024, 1024);
    // fc2: split-K x4 (Kc=1024), raw fp32 partials; p0 = out
    gemm256<3, 4><<<256, dim3(512), 0, stream>>>(gbuf, wfc2T, nullptr, nullptr, out,
                                                 p1, p2, p3, 4096, 1024, 4096, 1024);
    reduce4<<<4096, blk, 0, stream>>>(p1, p2, p3, b_fc2, x1, out);
}